// Round 10
// baseline (175.790 us; speedup 1.0000x reference)
//
#include <hip/hip_runtime.h>
#include <hip/hip_bf16.h>
#include <cstdint>

#define NB 4
#define NQ 512
#define NM 8192
#define NH 8
#define DH 64

typedef short bf16x8s __attribute__((ext_vector_type(8)));
typedef short bf16x4s __attribute__((ext_vector_type(4)));
typedef float f32x4  __attribute__((ext_vector_type(4)));

// fast fp32->bf16 (round-half-up)
static __device__ __forceinline__ short f2bs(float f) {
    unsigned u = __builtin_bit_cast(unsigned, f);
    return (short)(unsigned short)((u + 0x8000u) >> 16);
}
// packed pair via v_perm_b32: lo16 = bf16(a), hi16 = bf16(b)
static __device__ __forceinline__ unsigned pk2(float a, float b) {
    unsigned au = __builtin_bit_cast(unsigned, a) + 0x8000u;
    unsigned bu = __builtin_bit_cast(unsigned, b) + 0x8000u;
    return __builtin_amdgcn_perm(bu, au, 0x07060302u);
}

#if __has_builtin(__builtin_amdgcn_exp2f)
static __device__ __forceinline__ float fexp2(float x) { return __builtin_amdgcn_exp2f(x); }
#else
static __device__ __forceinline__ float fexp2(float x) { return exp2f(x); }
#endif

// ---------------------------------------------------------------------------
// Weight prep: Wq/Wo [512,512], Wkv [256,1024] (fp32 [k][n]) -> bf16 MFMA
// B-fragment order: Wf[(n0*KS + ks)*64 + lane][j] = W[ks*32+quad*8+j][n0*16+m16]
// ---------------------------------------------------------------------------
__global__ __launch_bounds__(256) void prep_weights(
    const float* __restrict__ Wq, const float* __restrict__ Wo,
    const float* __restrict__ Wkv,
    short* __restrict__ Wqf, short* __restrict__ Wof, short* __restrict__ Wkvf)
{
    const int t = threadIdx.x;
    const int w = t >> 6, ln = t & 63;
    const int m16 = ln & 15, quad = ln >> 4;
    int f = blockIdx.x * 4 + w;           // 0..1535
    const float* src; short* dst; int N, KS, n0, ks;
    if (f < 512)       { src = Wq;  dst = Wqf;  N = 512;  KS = 16; n0 = f >> 4; ks = f & 15; }
    else if (f < 1024) { f -= 512;  src = Wo;  dst = Wof;  N = 512;  KS = 16; n0 = f >> 4; ks = f & 15; }
    else               { f -= 1024; src = Wkv; dst = Wkvf; N = 1024; KS = 8;  n0 = f >> 3; ks = f & 7; }
    const float* sp = src + (size_t)(ks * 32 + quad * 8) * N + n0 * 16 + m16;
    float v[8];
    #pragma unroll
    for (int j = 0; j < 8; ++j) v[j] = sp[(size_t)j * N];
    uint4 pkv = { pk2(v[0],v[1]), pk2(v[2],v[3]), pk2(v[4],v[5]), pk2(v[6],v[7]) };
    *(uint4*)(dst + ((size_t)(n0 * KS + ks) * 64 + ln) * 8) = pkv;
}

// ---------------------------------------------------------------------------
// Plain projection body (q = x @ Wq): 32x64 tile, BK=64, 256 threads (passed t).
// fp32 A via LDS convert staging (needed: x is fp32 input).
// ---------------------------------------------------------------------------
__device__ __forceinline__ void proj32_body(
    const float* __restrict__ A, const short* __restrict__ Wf,
    float* __restrict__ C, const float* __restrict__ bias,
    int tm, int tn, char* smemraw, int t)
{
    short* As = (short*)smemraw;        // 2 x [32][72]

    const int w = t >> 6, ln = t & 63;
    const int m16 = ln & 15, quad = ln >> 4;
    const int wm = w >> 1, wn = w & 1;

    const int ar = t >> 3, ac = (t & 7) << 3;      // A: 32 rows x 64 k

    const float* Ap = A + (size_t)(tm * 32 + ar) * 512 + ac;

    f32x4 acc[2] = {};

    {
        float4 a0 = *(const float4*)(Ap);
        float4 a1 = *(const float4*)(Ap + 4);
        uint4 wa = { pk2(a0.x,a0.y), pk2(a0.z,a0.w), pk2(a1.x,a1.y), pk2(a1.z,a1.w) };
        *(uint4*)&As[ar * 72 + ac] = wa;
    }

    #pragma unroll
    for (int k0 = 0; k0 < 512; k0 += 64) {
        short* Ab = As + ((k0 >> 6) & 1) * 2304;
        __syncthreads();

        bf16x8s bfr[2][2];
        #pragma unroll
        for (int ks = 0; ks < 2; ++ks)
            #pragma unroll
            for (int nt = 0; nt < 2; ++nt)
                bfr[ks][nt] = *(const bf16x8s*)(Wf +
                    ((size_t)((tn * 4 + wn * 2 + nt) * 16 + (k0 >> 5) + ks) * 64 + ln) * 8);

        bf16x8s afr[2];
        #pragma unroll
        for (int ks = 0; ks < 2; ++ks)
            afr[ks] = *(const bf16x8s*)&Ab[(wm * 16 + m16) * 72 + ks * 32 + quad * 8];

        float4 a0n, a1n;
        if (k0 + 64 < 512) {
            a0n = *(const float4*)(Ap + k0 + 64);
            a1n = *(const float4*)(Ap + k0 + 68);
        }

        #pragma unroll
        for (int ks = 0; ks < 2; ++ks)
            #pragma unroll
            for (int nt = 0; nt < 2; ++nt)
                acc[nt] = __builtin_amdgcn_mfma_f32_16x16x32_bf16(afr[ks], bfr[ks][nt], acc[nt], 0, 0, 0);

        if (k0 + 64 < 512) {
            short* Abn = As + ((((k0 >> 6) + 1) & 1)) * 2304;
            uint4 wa = { pk2(a0n.x,a0n.y), pk2(a0n.z,a0n.w), pk2(a1n.x,a1n.y), pk2(a1n.z,a1n.w) };
            *(uint4*)&Abn[ar * 72 + ac] = wa;
        }
    }

    const int row0 = tm * 32 + wm * 16 + quad * 4;
    const int col0 = tn * 64 + wn * 32;
    #pragma unroll
    for (int nt = 0; nt < 2; ++nt) {
        const int col = col0 + nt * 16 + m16;
        const float bb = bias ? bias[col] : 0.f;
        #pragma unroll
        for (int r = 0; r < 4; ++r)
            C[(size_t)(row0 + r) * 512 + col] = acc[nt][r] + bb;
    }
}

// ---------------------------------------------------------------------------
// kv GEMM body, LOW-VGPR variant (round-6, measured win): 128x128 tile,
// 512 threads (8 waves), per-wave 64x32 output (acc = 32 VGPR -> 64-VGPR
// occupancy tier). BK=32, K=256, single-buffer LDS, 2 barriers/step.
// ---------------------------------------------------------------------------
__device__ __forceinline__ void kv_body(
    const float* __restrict__ A, const short* __restrict__ Wkvf,
    short* __restrict__ Kf, short* __restrict__ Vf,
    int kvid, char* smemraw)
{
    short* As = (short*)smemraw;        // [128][40] shorts, 10240 B

    const int t  = threadIdx.x;         // 0..511
    const int tm  = ((kvid >> 6) << 3) | (kvid & 7);   // 0..255
    const int tn0 = (kvid >> 3) & 7;                   // 128-col tile, 0..7
    const int w  = t >> 6, ln = t & 63;
    const int m16 = ln & 15, quad = ln >> 4;
    const int wm = w & 1, wn = w >> 1;                 // wm: row half, wn: 0..3

    const int ar = t >> 2;            // 0..127
    const int ac = (t & 3) << 3;      // 0,8,16,24 floats

    const float* Abase = A + (size_t)(tm * 128 + ar) * 256 + ac;

    f32x4 acc[4][2] = {};

    for (int s = 0; s < 8; ++s) {
        float4 a0 = *(const float4*)(Abase + s * 32);
        float4 a1 = *(const float4*)(Abase + s * 32 + 4);
        __syncthreads();                 // prior step's readers done
        uint4 wa = { pk2(a0.x,a0.y), pk2(a0.z,a0.w), pk2(a1.x,a1.y), pk2(a1.z,a1.w) };
        *(uint4*)&As[ar * 40 + ac] = wa;
        __syncthreads();

        bf16x8s bfr[2];
        #pragma unroll
        for (int j = 0; j < 2; ++j)
            bfr[j] = *(const bf16x8s*)(Wkvf +
                ((size_t)((tn0 * 8 + wn * 2 + j) * 8 + s) * 64 + ln) * 8);

        #pragma unroll
        for (int i = 0; i < 4; ++i) {
            bf16x8s af = *(const bf16x8s*)&As[(wm * 64 + i * 16 + m16) * 40 + quad * 8];
            acc[i][0] = __builtin_amdgcn_mfma_f32_16x16x32_bf16(af, bfr[0], acc[i][0], 0, 0, 0);
            acc[i][1] = __builtin_amdgcn_mfma_f32_16x16x32_bf16(af, bfr[1], acc[i][1], 0, 0, 0);
        }
    }

    const int row0 = tm * 128;
    const int b    = row0 >> 13;
    const int mr0  = row0 & (NM - 1);
    const int g0   = mr0 >> 5;

    __syncthreads();                     // all As reads done; reuse smem
    short* S = (short*)smemraw + w * 1024;   // 2 KB per wave

    if (tn0 < 4) {
        // K: acc[i][j][r] = K[key = mr0+wm*64+i*16+quad*4+r][d = (wn&1)*32+j*16+m16]
        const int h = tn0 * 2 + (wn >> 1);
        short* Kp = Kf + (size_t)(b * NH + h) * (NM * DH);
        const int ksel = wn & 1;
        #pragma unroll
        for (int hf = 0; hf < 2; ++hf) {
            #pragma unroll
            for (int di = 0; di < 2; ++di) {
                const int i = hf * 2 + di;
                #pragma unroll
                for (int j = 0; j < 2; ++j) {
                    const int base = (quad & 1) * 512 + (j * 2 + (m16 >> 3)) * 128
                                   + ((di * 2 + (quad >> 1)) * 4) * 8 + (m16 & 7);
                    #pragma unroll
                    for (int r = 0; r < 4; ++r)
                        S[base + r * 8] = f2bs(acc[i][j][r]);
                }
            }
            const int g = g0 + wm * 2 + hf;
            #pragma unroll
            for (int fl = 0; fl < 2; ++fl) {
                uint4 v = *(const uint4*)&S[fl * 512 + ln * 8];
                *(uint4*)(Kp + ((size_t)((g * 2 + fl) * 2 + ksel) * 512 + ln * 8)) = v;
            }
        }
    } else {
        // V: acc[i][j][r] = V[key = mr0+wm*64+i*16+quad*4+r][d = (wn&1)*32+j*16+m16]
        const int h = (tn0 - 4) * 2 + (wn >> 1);
        short* Vp = Vf + (size_t)(b * NH + h) * (NM * DH);
        #pragma unroll
        for (int hf = 0; hf < 2; ++hf) {
            #pragma unroll
            for (int di = 0; di < 2; ++di) {
                const int i = hf * 2 + di;
                #pragma unroll
                for (int j = 0; j < 2; ++j) {
                    const int base = j * 512
                                   + ((di * 2 + (quad >> 1)) * 16 + m16) * 8
                                   + (quad & 1) * 4;
                    #pragma unroll
                    for (int r = 0; r < 4; ++r)
                        S[base + r] = f2bs(acc[i][j][r]);
                }
            }
            const int g = g0 + wm * 2 + hf;
            #pragma unroll
            for (int fl = 0; fl < 2; ++fl) {
                uint4 v = *(const uint4*)&S[fl * 512 + ln * 8];
                *(uint4*)(Vp + ((size_t)((((wn & 1) * 2 + fl) * 256 + g) * 64 + ln) * 8)) = v;
            }
        }
    }
}

// ---------------------------------------------------------------------------
// Uber kernel, 512 threads: blocks 0..255 = q-proj (2 x 32x64 units),
// blocks 256..2303 = kv (128x128 tiles, 8 waves).
// ---------------------------------------------------------------------------
__global__ __launch_bounds__(512, 4) void gemm_kvq(
    const float* __restrict__ x,   const short* __restrict__ Wqf, float* __restrict__ q,
    const float* __restrict__ ctx, const short* __restrict__ Wkvf,
    short* __restrict__ Kf, short* __restrict__ Vf)
{
    __shared__ __align__(16) char smem[18432];
    if (blockIdx.x < 256) {
        const int u = (int)(blockIdx.x * 2) + (int)(threadIdx.x >> 8);
        proj32_body(x, Wqf, q, nullptr, u >> 3, u & 7,
                    smem + (threadIdx.x >> 8) * 9216, (int)(threadIdx.x & 255));
    } else {
        kv_body(ctx, Wkvf, Kf, Vf, (int)(blockIdx.x - 256), smem);
    }
}

// ---------------------------------------------------------------------------
// Out-projection, bf16-A direct-load variant: A is bf16 [2048][512] (written
// by attn in normal row-major order). Each lane loads its A-fragment with ONE
// bf16x8 global load -> no LDS, no barriers, no conversion in the k-loop.
// ---------------------------------------------------------------------------
__global__ __launch_bounds__(256) void gemm_projb(
    const short* __restrict__ Ab, const short* __restrict__ Wf,
    float* __restrict__ C, const float* __restrict__ bias)
{
    const int tm = (int)(blockIdx.x >> 3), tn = (int)(blockIdx.x & 7);
    const int t = (int)threadIdx.x;
    const int w = t >> 6, ln = t & 63;
    const int m16 = ln & 15, quad = ln >> 4;
    const int wm = w >> 1, wn = w & 1;

    const short* Ap = Ab + (size_t)(tm * 32 + wm * 16 + m16) * 512 + quad * 8;

    f32x4 acc[2] = {};

    #pragma unroll
    for (int k0 = 0; k0 < 512; k0 += 64) {
        bf16x8s bfr[2][2];
        #pragma unroll
        for (int ks = 0; ks < 2; ++ks)
            #pragma unroll
            for (int nt = 0; nt < 2; ++nt)
                bfr[ks][nt] = *(const bf16x8s*)(Wf +
                    ((size_t)((tn * 4 + wn * 2 + nt) * 16 + (k0 >> 5) + ks) * 64 + ln) * 8);

        bf16x8s afr[2];
        #pragma unroll
        for (int ks = 0; ks < 2; ++ks)
            afr[ks] = *(const bf16x8s*)(Ap + k0 + ks * 32);

        #pragma unroll
        for (int ks = 0; ks < 2; ++ks)
            #pragma unroll
            for (int nt = 0; nt < 2; ++nt)
                acc[nt] = __builtin_amdgcn_mfma_f32_16x16x32_bf16(afr[ks], bfr[ks][nt], acc[nt], 0, 0, 0);
    }

    const int row0 = tm * 32 + wm * 16 + quad * 4;
    const int col0 = tn * 64 + wn * 32;
    #pragma unroll
    for (int nt = 0; nt < 2; ++nt) {
        const int col = col0 + nt * 16 + m16;
        const float bb = bias[col];
        #pragma unroll
        for (int r = 0; r < 4; ++r)
            C[(size_t)(row0 + r) * 512 + col] = acc[nt][r] + bb;
    }
}

// ---------------------------------------------------------------------------
// MFMA flash attention: 32-row q-tiles, full keys, 8 waves (512 thr),
// 512 blocks (2 blocks/CU).  K=32 PV via key-permuted fragments.
// __launch_bounds__(512, 2): grid limits us to 2 blocks/CU anyway, so the
// 128-VGPR tier is free occupancy-wise and lets the compiler keep BOTH the
// K and the (new, explicit) V double-buffer prefetches in flight -- at the
// old 64-reg cap it sank prefetch loads to their uses (r9: VGPR=64 with a
// >100-reg nominal live set, both pipes <37% busy => serial-latency-bound).
// st C-seed hoisted (loop-invariant zero) to kill per-iter zero-init VALU.
// NO setprio (r8: fences at a VGPR cap => catastrophic spill).
// Output: normalized bf16 [2048][512].
// ---------------------------------------------------------------------------
__global__ __launch_bounds__(512, 2) void attn_mfma(
    const float* __restrict__ Q,    // [2048, 512] fp32
    const short* __restrict__ Kfr,  // fragment-order K (permuted keys)
    const short* __restrict__ Vfr,  // fragment-order V (K=32 A-op, V^T)
    short* __restrict__ Ogb)        // [2048, 512] bf16
{
    __shared__ __align__(16) float Ob[2][32 * 66];   // 16.9 KB
    __shared__ float lbuf[8 * 32];

    const int bid = blockIdx.x;
    const int xcd = bid & 7, g = bid >> 3;
    const int bh  = xcd * 4 + (g & 3);     // 16 qt-blocks of one bh share bid%8
    const int qt  = g >> 2;                // 0..15 (32-row tiles)
    const int b   = bh >> 3, h = bh & 7;
    const int t   = threadIdx.x;
    const int w   = t >> 6, ln = t & 63;
    const int m16 = ln & 15, quad = ln >> 4;

    const short* Kbase = Kfr + (size_t)bh * (NM * DH);
    const short* Vbase = Vfr + (size_t)bh * (NM * DH);

    // Q scaled by (1/8) * log2(e)  -> scores in log2 domain
    const float qsc = 0.125f * 1.44269504f;
    bf16x8s qf[2][2];
    #pragma unroll
    for (int mt = 0; mt < 2; ++mt) {
        const float* qrow = Q + ((size_t)(b * NQ + qt * 32 + mt * 16 + m16)) * 512 + h * 64;
        #pragma unroll
        for (int ks = 0; ks < 2; ++ks) {
            float4 x0 = *(const float4*)(qrow + ks * 32 + quad * 8);
            float4 x1 = *(const float4*)(qrow + ks * 32 + quad * 8 + 4);
            uint4 pkv = { pk2(x0.x * qsc, x0.y * qsc), pk2(x0.z * qsc, x0.w * qsc),
                          pk2(x1.x * qsc, x1.y * qsc), pk2(x1.z * qsc, x1.w * qsc) };
            qf[mt][ks] = *reinterpret_cast<bf16x8s*>(&pkv);
        }
    }

    bf16x8s ones8;
    #pragma unroll
    for (int j = 0; j < 8; ++j) ones8[j] = (short)0x3F80;

    const f32x4 zf = {};                 // hoisted zero C-seed for S tiles

    f32x4 o[2][4] = {};
    f32x4 lsum[2] = {};

    bf16x8s kf[4][2];
    {
        const int kc = w * 64;
        #pragma unroll
        for (int nt = 0; nt < 4; ++nt)
            #pragma unroll
            for (int ks = 0; ks < 2; ++ks)
                kf[nt][ks] = *(const bf16x8s*)(Kbase + ((((kc >> 4) + nt) * 2 + ks) << 9) + ln * 8);
    }

    // V double buffer: vaA holds iteration it, vaB gets it+1 (and swap roles)
    bf16x8s vaA[4][2], vaB[4][2];
    {
        const int kc = w * 64;
        #pragma unroll
        for (int dt = 0; dt < 4; ++dt)
            #pragma unroll
            for (int gg = 0; gg < 2; ++gg)
                vaA[dt][gg] = *(const bf16x8s*)(Vbase + ((size_t)(dt * 256 + (kc >> 5) + gg) * 64 + ln) * 8);
    }

    auto run_iter = [&](int it, bf16x8s (&vc)[4][2], bf16x8s (&vn)[4][2]) {
        // S^T : 16x16x32, C rows = permuted keys (key quad*8 + t*4 + r)
        f32x4 st[2][4];
        #pragma unroll
        for (int kt = 0; kt < 4; ++kt)
            #pragma unroll
            for (int mt = 0; mt < 2; ++mt) {
                st[mt][kt] = __builtin_amdgcn_mfma_f32_16x16x32_bf16(kf[kt][0], qf[mt][0], zf, 0, 0, 0);
                st[mt][kt] = __builtin_amdgcn_mfma_f32_16x16x32_bf16(kf[kt][1], qf[mt][1], st[mt][kt], 0, 0, 0);
            }

        // prefetch K and V fragments for it+1 (in flight across exp/pack+PV)
        if (it + 1 < 16) {
            const int kn = (it + 1) * 512 + w * 64;
            #pragma unroll
            for (int nt = 0; nt < 4; ++nt)
                #pragma unroll
                for (int ks = 0; ks < 2; ++ks)
                    kf[nt][ks] = *(const bf16x8s*)(Kbase + ((((kn >> 4) + nt) * 2 + ks) << 9) + ln * 8);
            #pragma unroll
            for (int dt = 0; dt < 4; ++dt)
                #pragma unroll
                for (int gg = 0; gg < 2; ++gg)
                    vn[dt][gg] = *(const bf16x8s*)(Vbase + ((size_t)(dt * 256 + (kn >> 5) + gg) * 64 + ln) * 8);
        }

        // p = 2^s; the two S-tiles of a group pack into one K=32 B-operand
        #pragma unroll
        for (int mt = 0; mt < 2; ++mt)
            #pragma unroll
            for (int gg = 0; gg < 2; ++gg) {
                const f32x4 s0 = st[mt][2 * gg];
                const f32x4 s1 = st[mt][2 * gg + 1];
                uint4 pu = { pk2(fexp2(s0[0]), fexp2(s0[1])), pk2(fexp2(s0[2]), fexp2(s0[3])),
                             pk2(fexp2(s1[0]), fexp2(s1[1])), pk2(fexp2(s1[2]), fexp2(s1[3])) };
                bf16x8s pbv = *reinterpret_cast<bf16x8s*>(&pu);
                #pragma unroll
                for (int dt = 0; dt < 4; ++dt)
                    o[mt][dt] = __builtin_amdgcn_mfma_f32_16x16x32_bf16(vc[dt][gg], pbv, o[mt][dt], 0, 0, 0);
                lsum[mt] = __builtin_amdgcn_mfma_f32_16x16x32_bf16(ones8, pbv, lsum[mt], 0, 0, 0);
            }
    };

    for (int ith = 0; ith < 8; ++ith) {
        run_iter(2 * ith,     vaA, vaB);
        run_iter(2 * ith + 1, vaB, vaA);
    }

    // ---- epilogue: l partials + 8-wave 2-buffer O merge ----
    if (quad == 0) {
        #pragma unroll
        for (int mt = 0; mt < 2; ++mt)
            lbuf[w * 32 + mt * 16 + m16] = lsum[mt][0];
    }
    // Phase A: waves 0,1 write buffers 0,1
    if (w < 2) {
        float* dst = Ob[w];
        #pragma unroll
        for (int mt = 0; mt < 2; ++mt)
            #pragma unroll
            for (int dt = 0; dt < 4; ++dt)
                *(f32x4*)&dst[(mt * 16 + m16) * 66 + dt * 16 + quad * 4] = o[mt][dt];
    }
    __syncthreads();
    // Phases B..D: waves {2,3}, {4,5}, {6,7} add into buffers 0,1
    #pragma unroll
    for (int ph = 1; ph < 4; ++ph) {
        if ((w >> 1) == ph) {
            float* dst = Ob[w & 1];
            #pragma unroll
            for (int mt = 0; mt < 2; ++mt)
                #pragma unroll
                for (int dt = 0; dt < 4; ++dt) {
                    float* p = &dst[(mt * 16 + m16) * 66 + dt * 16 + quad * 4];
                    f32x4 cur = *(f32x4*)p;
                    cur += o[mt][dt];
                    *(f32x4*)p = cur;
                }
        }
        __syncthreads();
    }
    // Final: combine the two buffers, normalize, store bf16 (512 threads)
    {
        const int row = t >> 4;             // 0..31
        const int d0  = (t & 15) << 2;      // 4 bf16 per thread
        float l = 0.f;
        #pragma unroll
        for (int wi = 0; wi < 8; ++wi) l += lbuf[wi * 32 + row];
        const float inv = 1.0f / l;
        const int c = row * 66 + d0;
        const float v0 = (Ob[0][c + 0] + Ob[1][c + 0]) * inv;
        const float v1 = (Ob[0][c + 1] + Ob[1][c + 1]) * inv;
        const float v2 = (Ob[0][c + 2] + Ob[1][c + 2]) * inv;
        const float v3 = (Ob[0][c + 3] + Ob[1][c + 3]) * inv;
        uint2 rv = { pk2(v0, v1), pk2(v2, v3) };
        short* op = Ogb + ((size_t)(b * NQ + qt * 32 + row)) * 512 + h * 64 + d0;
        *(uint2*)op = rv;
    }
}

// ---------------------------------------------------------------------------
extern "C" void kernel_launch(void* const* d_in, const int* in_sizes, int n_in,
                              void* d_out, int out_size, void* d_ws, size_t ws_size,
                              hipStream_t stream) {
    (void)in_sizes; (void)n_in; (void)out_size; (void)ws_size;

    const float* x   = (const float*)d_in[0];   // [4, 512, 512]
    const float* ctx = (const float*)d_in[1];   // [4, 8192, 256]
    const float* Wq  = (const float*)d_in[2];   // [512, 512]
    const float* Wkv = (const float*)d_in[3];   // [256, 1024]
    const float* Wo  = (const float*)d_in[4];   // [512, 512]
    const float* bo  = (const float*)d_in[5];   // [512]
    float* out = (float*)d_out;                 // [4, 512, 512]

    float* ws    = (float*)d_ws;
    float* q     = ws;                                       // 4 MB fp32
    short* attnb = (short*)(q + (size_t)2048 * 512);         // 2 MB bf16
    short* Kf    = attnb + (size_t)2048 * 512;               // 33.5 MB bf16 (fragment order)
    short* Vf    = Kf + (size_t)NB * NH * NM * DH;           // 33.5 MB bf16 (fragment order)
    short* Wqf   = Vf + (size_t)NB * NH * NM * DH;           // 512 KB
    short* Wof   = Wqf + (size_t)512 * 512;                  // 512 KB
    short* Wkvf  = Wof + (size_t)512 * 512;                  // 512 KB

    // weights -> bf16 fragment order
    prep_weights<<<dim3(384), dim3(256), 0, stream>>>(Wq, Wo, Wkv, Wqf, Wof, Wkvf);

    // q = x@Wq (256 blocks x 2 units) + kv = ctx@Wkv (2048 blocks), 512 thr
    gemm_kvq<<<dim3(2304), dim3(512), 0, stream>>>(x, Wqf, q, ctx, Wkvf, Kf, Vf);

    // flash attention: 32 bh x 16 q-tiles = 512 blocks x 512 threads
    attn_mfma<<<dim3(512), dim3(512), 0, stream>>>(q, Kf, Vf, attnb);

    // out = attnb @ Wo + bo (512 blocks, LDS-free bf16-A path)
    gemm_projb<<<dim3(512), dim3(256), 0, stream>>>(attnb, Wof, out, bo);
}

// Round 11
// 168.590 us; speedup vs baseline: 1.0427x; 1.0427x over previous
//
#include <hip/hip_runtime.h>
#include <hip/hip_bf16.h>
#include <cstdint>

#define NB 4
#define NQ 512
#define NM 8192
#define NH 8
#define DH 64

typedef short bf16x8s __attribute__((ext_vector_type(8)));
typedef short bf16x4s __attribute__((ext_vector_type(4)));
typedef float f32x4  __attribute__((ext_vector_type(4)));

// fast fp32->bf16 (round-half-up)
static __device__ __forceinline__ short f2bs(float f) {
    unsigned u = __builtin_bit_cast(unsigned, f);
    return (short)(unsigned short)((u + 0x8000u) >> 16);
}
// packed pair via v_perm_b32: lo16 = bf16(a), hi16 = bf16(b)
static __device__ __forceinline__ unsigned pk2(float a, float b) {
    unsigned au = __builtin_bit_cast(unsigned, a) + 0x8000u;
    unsigned bu = __builtin_bit_cast(unsigned, b) + 0x8000u;
    return __builtin_amdgcn_perm(bu, au, 0x07060302u);
}

#if __has_builtin(__builtin_amdgcn_exp2f)
static __device__ __forceinline__ float fexp2(float x) { return __builtin_amdgcn_exp2f(x); }
#else
static __device__ __forceinline__ float fexp2(float x) { return exp2f(x); }
#endif

// ---------------------------------------------------------------------------
// Weight prep: Wq/Wo [512,512], Wkv [256,1024] (fp32 [k][n]) -> bf16 MFMA
// B-fragment order: Wf[(n0*KS + ks)*64 + lane][j] = W[ks*32+quad*8+j][n0*16+m16]
// ---------------------------------------------------------------------------
__global__ __launch_bounds__(256) void prep_weights(
    const float* __restrict__ Wq, const float* __restrict__ Wo,
    const float* __restrict__ Wkv,
    short* __restrict__ Wqf, short* __restrict__ Wof, short* __restrict__ Wkvf)
{
    const int t = threadIdx.x;
    const int w = t >> 6, ln = t & 63;
    const int m16 = ln & 15, quad = ln >> 4;
    int f = blockIdx.x * 4 + w;           // 0..1535
    const float* src; short* dst; int N, KS, n0, ks;
    if (f < 512)       { src = Wq;  dst = Wqf;  N = 512;  KS = 16; n0 = f >> 4; ks = f & 15; }
    else if (f < 1024) { f -= 512;  src = Wo;  dst = Wof;  N = 512;  KS = 16; n0 = f >> 4; ks = f & 15; }
    else               { f -= 1024; src = Wkv; dst = Wkvf; N = 1024; KS = 8;  n0 = f >> 3; ks = f & 7; }
    const float* sp = src + (size_t)(ks * 32 + quad * 8) * N + n0 * 16 + m16;
    float v[8];
    #pragma unroll
    for (int j = 0; j < 8; ++j) v[j] = sp[(size_t)j * N];
    uint4 pkv = { pk2(v[0],v[1]), pk2(v[2],v[3]), pk2(v[4],v[5]), pk2(v[6],v[7]) };
    *(uint4*)(dst + ((size_t)(n0 * KS + ks) * 64 + ln) * 8) = pkv;
}

// ---------------------------------------------------------------------------
// Plain projection body (q = x @ Wq): 32x64 tile, BK=64, 256 threads (passed t).
// fp32 A via LDS convert staging (needed: x is fp32 input).
// ---------------------------------------------------------------------------
__device__ __forceinline__ void proj32_body(
    const float* __restrict__ A, const short* __restrict__ Wf,
    float* __restrict__ C, const float* __restrict__ bias,
    int tm, int tn, char* smemraw, int t)
{
    short* As = (short*)smemraw;        // 2 x [32][72]

    const int w = t >> 6, ln = t & 63;
    const int m16 = ln & 15, quad = ln >> 4;
    const int wm = w >> 1, wn = w & 1;

    const int ar = t >> 3, ac = (t & 7) << 3;      // A: 32 rows x 64 k

    const float* Ap = A + (size_t)(tm * 32 + ar) * 512 + ac;

    f32x4 acc[2] = {};

    {
        float4 a0 = *(const float4*)(Ap);
        float4 a1 = *(const float4*)(Ap + 4);
        uint4 wa = { pk2(a0.x,a0.y), pk2(a0.z,a0.w), pk2(a1.x,a1.y), pk2(a1.z,a1.w) };
        *(uint4*)&As[ar * 72 + ac] = wa;
    }

    #pragma unroll
    for (int k0 = 0; k0 < 512; k0 += 64) {
        short* Ab = As + ((k0 >> 6) & 1) * 2304;
        __syncthreads();

        bf16x8s bfr[2][2];
        #pragma unroll
        for (int ks = 0; ks < 2; ++ks)
            #pragma unroll
            for (int nt = 0; nt < 2; ++nt)
                bfr[ks][nt] = *(const bf16x8s*)(Wf +
                    ((size_t)((tn * 4 + wn * 2 + nt) * 16 + (k0 >> 5) + ks) * 64 + ln) * 8);

        bf16x8s afr[2];
        #pragma unroll
        for (int ks = 0; ks < 2; ++ks)
            afr[ks] = *(const bf16x8s*)&Ab[(wm * 16 + m16) * 72 + ks * 32 + quad * 8];

        float4 a0n, a1n;
        if (k0 + 64 < 512) {
            a0n = *(const float4*)(Ap + k0 + 64);
            a1n = *(const float4*)(Ap + k0 + 68);
        }

        #pragma unroll
        for (int ks = 0; ks < 2; ++ks)
            #pragma unroll
            for (int nt = 0; nt < 2; ++nt)
                acc[nt] = __builtin_amdgcn_mfma_f32_16x16x32_bf16(afr[ks], bfr[ks][nt], acc[nt], 0, 0, 0);

        if (k0 + 64 < 512) {
            short* Abn = As + ((((k0 >> 6) + 1) & 1)) * 2304;
            uint4 wa = { pk2(a0n.x,a0n.y), pk2(a0n.z,a0n.w), pk2(a1n.x,a1n.y), pk2(a1n.z,a1n.w) };
            *(uint4*)&Abn[ar * 72 + ac] = wa;
        }
    }

    const int row0 = tm * 32 + wm * 16 + quad * 4;
    const int col0 = tn * 64 + wn * 32;
    #pragma unroll
    for (int nt = 0; nt < 2; ++nt) {
        const int col = col0 + nt * 16 + m16;
        const float bb = bias ? bias[col] : 0.f;
        #pragma unroll
        for (int r = 0; r < 4; ++r)
            C[(size_t)(row0 + r) * 512 + col] = acc[nt][r] + bb;
    }
}

// ---------------------------------------------------------------------------
// kv GEMM body, LOW-VGPR variant (round-6, measured win): 128x128 tile,
// 512 threads (8 waves), per-wave 64x32 output (acc = 32 VGPR -> 64-VGPR
// occupancy tier). BK=32, K=256, single-buffer LDS, 2 barriers/step.
// ---------------------------------------------------------------------------
__device__ __forceinline__ void kv_body(
    const float* __restrict__ A, const short* __restrict__ Wkvf,
    short* __restrict__ Kf, short* __restrict__ Vf,
    int kvid, char* smemraw)
{
    short* As = (short*)smemraw;        // [128][40] shorts, 10240 B

    const int t  = threadIdx.x;         // 0..511
    const int tm  = ((kvid >> 6) << 3) | (kvid & 7);   // 0..255
    const int tn0 = (kvid >> 3) & 7;                   // 128-col tile, 0..7
    const int w  = t >> 6, ln = t & 63;
    const int m16 = ln & 15, quad = ln >> 4;
    const int wm = w & 1, wn = w >> 1;                 // wm: row half, wn: 0..3

    const int ar = t >> 2;            // 0..127
    const int ac = (t & 3) << 3;      // 0,8,16,24 floats

    const float* Abase = A + (size_t)(tm * 128 + ar) * 256 + ac;

    f32x4 acc[4][2] = {};

    for (int s = 0; s < 8; ++s) {
        float4 a0 = *(const float4*)(Abase + s * 32);
        float4 a1 = *(const float4*)(Abase + s * 32 + 4);
        __syncthreads();                 // prior step's readers done
        uint4 wa = { pk2(a0.x,a0.y), pk2(a0.z,a0.w), pk2(a1.x,a1.y), pk2(a1.z,a1.w) };
        *(uint4*)&As[ar * 40 + ac] = wa;
        __syncthreads();

        bf16x8s bfr[2];
        #pragma unroll
        for (int j = 0; j < 2; ++j)
            bfr[j] = *(const bf16x8s*)(Wkvf +
                ((size_t)((tn0 * 8 + wn * 2 + j) * 8 + s) * 64 + ln) * 8);

        #pragma unroll
        for (int i = 0; i < 4; ++i) {
            bf16x8s af = *(const bf16x8s*)&As[(wm * 64 + i * 16 + m16) * 40 + quad * 8];
            acc[i][0] = __builtin_amdgcn_mfma_f32_16x16x32_bf16(af, bfr[0], acc[i][0], 0, 0, 0);
            acc[i][1] = __builtin_amdgcn_mfma_f32_16x16x32_bf16(af, bfr[1], acc[i][1], 0, 0, 0);
        }
    }

    const int row0 = tm * 128;
    const int b    = row0 >> 13;
    const int mr0  = row0 & (NM - 1);
    const int g0   = mr0 >> 5;

    __syncthreads();                     // all As reads done; reuse smem
    short* S = (short*)smemraw + w * 1024;   // 2 KB per wave

    if (tn0 < 4) {
        // K: acc[i][j][r] = K[key = mr0+wm*64+i*16+quad*4+r][d = (wn&1)*32+j*16+m16]
        const int h = tn0 * 2 + (wn >> 1);
        short* Kp = Kf + (size_t)(b * NH + h) * (NM * DH);
        const int ksel = wn & 1;
        #pragma unroll
        for (int hf = 0; hf < 2; ++hf) {
            #pragma unroll
            for (int di = 0; di < 2; ++di) {
                const int i = hf * 2 + di;
                #pragma unroll
                for (int j = 0; j < 2; ++j) {
                    const int base = (quad & 1) * 512 + (j * 2 + (m16 >> 3)) * 128
                                   + ((di * 2 + (quad >> 1)) * 4) * 8 + (m16 & 7);
                    #pragma unroll
                    for (int r = 0; r < 4; ++r)
                        S[base + r * 8] = f2bs(acc[i][j][r]);
                }
            }
            const int g = g0 + wm * 2 + hf;
            #pragma unroll
            for (int fl = 0; fl < 2; ++fl) {
                uint4 v = *(const uint4*)&S[fl * 512 + ln * 8];
                *(uint4*)(Kp + ((size_t)((g * 2 + fl) * 2 + ksel) * 512 + ln * 8)) = v;
            }
        }
    } else {
        // V: acc[i][j][r] = V[key = mr0+wm*64+i*16+quad*4+r][d = (wn&1)*32+j*16+m16]
        const int h = (tn0 - 4) * 2 + (wn >> 1);
        short* Vp = Vf + (size_t)(b * NH + h) * (NM * DH);
        #pragma unroll
        for (int hf = 0; hf < 2; ++hf) {
            #pragma unroll
            for (int di = 0; di < 2; ++di) {
                const int i = hf * 2 + di;
                #pragma unroll
                for (int j = 0; j < 2; ++j) {
                    const int base = j * 512
                                   + ((di * 2 + (quad >> 1)) * 16 + m16) * 8
                                   + (quad & 1) * 4;
                    #pragma unroll
                    for (int r = 0; r < 4; ++r)
                        S[base + r] = f2bs(acc[i][j][r]);
                }
            }
            const int g = g0 + wm * 2 + hf;
            #pragma unroll
            for (int fl = 0; fl < 2; ++fl) {
                uint4 v = *(const uint4*)&S[fl * 512 + ln * 8];
                *(uint4*)(Vp + ((size_t)((((wn & 1) * 2 + fl) * 256 + g) * 64 + ln) * 8)) = v;
            }
        }
    }
}

// ---------------------------------------------------------------------------
// Uber kernel, 512 threads: blocks 0..255 = q-proj (2 x 32x64 units),
// blocks 256..2303 = kv (128x128 tiles, 8 waves).
// ---------------------------------------------------------------------------
__global__ __launch_bounds__(512, 4) void gemm_kvq(
    const float* __restrict__ x,   const short* __restrict__ Wqf, float* __restrict__ q,
    const float* __restrict__ ctx, const short* __restrict__ Wkvf,
    short* __restrict__ Kf, short* __restrict__ Vf)
{
    __shared__ __align__(16) char smem[18432];
    if (blockIdx.x < 256) {
        const int u = (int)(blockIdx.x * 2) + (int)(threadIdx.x >> 8);
        proj32_body(x, Wqf, q, nullptr, u >> 3, u & 7,
                    smem + (threadIdx.x >> 8) * 9216, (int)(threadIdx.x & 255));
    } else {
        kv_body(ctx, Wkvf, Kf, Vf, (int)(blockIdx.x - 256), smem);
    }
}

// ---------------------------------------------------------------------------
// Out-projection, bf16-A LDS-staged variant: A is bf16 [2048][512] written by
// attn. COALESCED uint4 row loads (threads 0..7 cover one row's 64 shorts
// contiguously) -> LDS -> fragment reads. Replaces r9's gemm_projb whose
// per-lane direct fragment gather strided 1 KB between consecutive lanes
// (uncoalesced; measured ~= old fp32 proj32). No fp32->bf16 convert needed.
// Double-buffered, proven proj32 barrier pattern (1 barrier/step).
// ---------------------------------------------------------------------------
__global__ __launch_bounds__(256) void gemm_projo(
    const short* __restrict__ Ab, const short* __restrict__ Wf,
    float* __restrict__ C, const float* __restrict__ bias)
{
    __shared__ __align__(16) short As[2][32 * 72];   // 9216 B

    const int tm = (int)(blockIdx.x >> 3), tn = (int)(blockIdx.x & 7);
    const int t = (int)threadIdx.x;
    const int w = t >> 6, ln = t & 63;
    const int m16 = ln & 15, quad = ln >> 4;
    const int wm = w >> 1, wn = w & 1;

    const int ar = t >> 3, ac = (t & 7) << 3;       // 32 rows x 64 shorts

    const short* Ap = Ab + (size_t)(tm * 32 + ar) * 512 + ac;

    f32x4 acc[2] = {};

    {   // prologue: stage k0=0 into buffer 0 (one coalesced uint4 per thread)
        uint4 wa = *(const uint4*)(Ap);
        *(uint4*)&As[0][ar * 72 + ac] = wa;
    }

    #pragma unroll
    for (int k0 = 0; k0 < 512; k0 += 64) {
        short* Abuf = As[(k0 >> 6) & 1];
        __syncthreads();

        bf16x8s bfr[2][2];
        #pragma unroll
        for (int ks = 0; ks < 2; ++ks)
            #pragma unroll
            for (int nt = 0; nt < 2; ++nt)
                bfr[ks][nt] = *(const bf16x8s*)(Wf +
                    ((size_t)((tn * 4 + wn * 2 + nt) * 16 + (k0 >> 5) + ks) * 64 + ln) * 8);

        bf16x8s afr[2];
        #pragma unroll
        for (int ks = 0; ks < 2; ++ks)
            afr[ks] = *(const bf16x8s*)&Abuf[(wm * 16 + m16) * 72 + ks * 32 + quad * 8];

        uint4 an;
        if (k0 + 64 < 512)
            an = *(const uint4*)(Ap + k0 + 64);

        #pragma unroll
        for (int ks = 0; ks < 2; ++ks)
            #pragma unroll
            for (int nt = 0; nt < 2; ++nt)
                acc[nt] = __builtin_amdgcn_mfma_f32_16x16x32_bf16(afr[ks], bfr[ks][nt], acc[nt], 0, 0, 0);

        if (k0 + 64 < 512)
            *(uint4*)&As[((k0 >> 6) + 1) & 1][ar * 72 + ac] = an;
    }

    const int row0 = tm * 32 + wm * 16 + quad * 4;
    const int col0 = tn * 64 + wn * 32;
    #pragma unroll
    for (int nt = 0; nt < 2; ++nt) {
        const int col = col0 + nt * 16 + m16;
        const float bb = bias[col];
        #pragma unroll
        for (int r = 0; r < 4; ++r)
            C[(size_t)(row0 + r) * 512 + col] = acc[nt][r] + bb;
    }
}

// ---------------------------------------------------------------------------
// MFMA flash attention (EXACT round-9 source -- measured 55.0 us, VGPR 64,
// clean FETCH/WRITE; five perturbations (occupancy up, traffic down, regs up,
// setprio, explicit dbuf) all null or negative => frozen):
// 32-row q-tiles, full keys, 8 waves (512 thr), 512 blocks.
// K=32 PV via key-permuted fragments. Output: normalized bf16 [2048][512].
// ---------------------------------------------------------------------------
__global__ __launch_bounds__(512, 4) void attn_mfma(
    const float* __restrict__ Q,    // [2048, 512] fp32
    const short* __restrict__ Kfr,  // fragment-order K (permuted keys)
    const short* __restrict__ Vfr,  // fragment-order V (K=32 A-op, V^T)
    short* __restrict__ Ogb)        // [2048, 512] bf16
{
    __shared__ __align__(16) float Ob[2][32 * 66];   // 16.9 KB
    __shared__ float lbuf[8 * 32];

    const int bid = blockIdx.x;
    const int xcd = bid & 7, g = bid >> 3;
    const int bh  = xcd * 4 + (g & 3);     // 16 qt-blocks of one bh share bid%8
    const int qt  = g >> 2;                // 0..15 (32-row tiles)
    const int b   = bh >> 3, h = bh & 7;
    const int t   = threadIdx.x;
    const int w   = t >> 6, ln = t & 63;
    const int m16 = ln & 15, quad = ln >> 4;

    const short* Kbase = Kfr + (size_t)bh * (NM * DH);
    const short* Vbase = Vfr + (size_t)bh * (NM * DH);

    // Q scaled by (1/8) * log2(e)  -> scores in log2 domain
    const float qsc = 0.125f * 1.44269504f;
    bf16x8s qf[2][2];
    #pragma unroll
    for (int mt = 0; mt < 2; ++mt) {
        const float* qrow = Q + ((size_t)(b * NQ + qt * 32 + mt * 16 + m16)) * 512 + h * 64;
        #pragma unroll
        for (int ks = 0; ks < 2; ++ks) {
            float4 x0 = *(const float4*)(qrow + ks * 32 + quad * 8);
            float4 x1 = *(const float4*)(qrow + ks * 32 + quad * 8 + 4);
            uint4 pkv = { pk2(x0.x * qsc, x0.y * qsc), pk2(x0.z * qsc, x0.w * qsc),
                          pk2(x1.x * qsc, x1.y * qsc), pk2(x1.z * qsc, x1.w * qsc) };
            qf[mt][ks] = *reinterpret_cast<bf16x8s*>(&pkv);
        }
    }

    bf16x8s ones8;
    #pragma unroll
    for (int j = 0; j < 8; ++j) ones8[j] = (short)0x3F80;

    f32x4 o[2][4] = {};
    f32x4 lsum[2] = {};

    bf16x8s kf[4][2];
    {
        const int kc = w * 64;
        #pragma unroll
        for (int nt = 0; nt < 4; ++nt)
            #pragma unroll
            for (int ks = 0; ks < 2; ++ks)
                kf[nt][ks] = *(const bf16x8s*)(Kbase + ((((kc >> 4) + nt) * 2 + ks) << 9) + ln * 8);
    }

    for (int it = 0; it < 16; ++it) {
        const int kc = it * 512 + w * 64;

        // V frags: K=32 A-operands, one bf16x8 per (dt, group)
        bf16x8s va8[4][2];
        #pragma unroll
        for (int dt = 0; dt < 4; ++dt)
            #pragma unroll
            for (int gg = 0; gg < 2; ++gg)
                va8[dt][gg] = *(const bf16x8s*)(Vbase + ((size_t)(dt * 256 + (kc >> 5) + gg) * 64 + ln) * 8);

        // S^T : 16x16x32, C rows = permuted keys (key quad*8 + t*4 + r)
        f32x4 st[2][4] = {};
        #pragma unroll
        for (int kt = 0; kt < 4; ++kt)
            #pragma unroll
            for (int mt = 0; mt < 2; ++mt) {
                st[mt][kt] = __builtin_amdgcn_mfma_f32_16x16x32_bf16(kf[kt][0], qf[mt][0], st[mt][kt], 0, 0, 0);
                st[mt][kt] = __builtin_amdgcn_mfma_f32_16x16x32_bf16(kf[kt][1], qf[mt][1], st[mt][kt], 0, 0, 0);
            }

        if (it + 1 < 16) {
            const int kn = (it + 1) * 512 + w * 64;
            #pragma unroll
            for (int nt = 0; nt < 4; ++nt)
                #pragma unroll
                for (int ks = 0; ks < 2; ++ks)
                    kf[nt][ks] = *(const bf16x8s*)(Kbase + ((((kn >> 4) + nt) * 2 + ks) << 9) + ln * 8);
        }

        // p = 2^s; the two S-tiles of a group pack into one K=32 B-operand
        #pragma unroll
        for (int mt = 0; mt < 2; ++mt)
            #pragma unroll
            for (int gg = 0; gg < 2; ++gg) {
                const f32x4 s0 = st[mt][2 * gg];
                const f32x4 s1 = st[mt][2 * gg + 1];
                uint4 pu = { pk2(fexp2(s0[0]), fexp2(s0[1])), pk2(fexp2(s0[2]), fexp2(s0[3])),
                             pk2(fexp2(s1[0]), fexp2(s1[1])), pk2(fexp2(s1[2]), fexp2(s1[3])) };
                bf16x8s pbv = *reinterpret_cast<bf16x8s*>(&pu);
                #pragma unroll
                for (int dt = 0; dt < 4; ++dt)
                    o[mt][dt] = __builtin_amdgcn_mfma_f32_16x16x32_bf16(va8[dt][gg], pbv, o[mt][dt], 0, 0, 0);
                lsum[mt] = __builtin_amdgcn_mfma_f32_16x16x32_bf16(ones8, pbv, lsum[mt], 0, 0, 0);
            }
    }

    // ---- epilogue: l partials + 8-wave 2-buffer O merge ----
    if (quad == 0) {
        #pragma unroll
        for (int mt = 0; mt < 2; ++mt)
            lbuf[w * 32 + mt * 16 + m16] = lsum[mt][0];
    }
    // Phase A: waves 0,1 write buffers 0,1
    if (w < 2) {
        float* dst = Ob[w];
        #pragma unroll
        for (int mt = 0; mt < 2; ++mt)
            #pragma unroll
            for (int dt = 0; dt < 4; ++dt)
                *(f32x4*)&dst[(mt * 16 + m16) * 66 + dt * 16 + quad * 4] = o[mt][dt];
    }
    __syncthreads();
    // Phases B..D: waves {2,3}, {4,5}, {6,7} add into buffers 0,1
    #pragma unroll
    for (int ph = 1; ph < 4; ++ph) {
        if ((w >> 1) == ph) {
            float* dst = Ob[w & 1];
            #pragma unroll
            for (int mt = 0; mt < 2; ++mt)
                #pragma unroll
                for (int dt = 0; dt < 4; ++dt) {
                    float* p = &dst[(mt * 16 + m16) * 66 + dt * 16 + quad * 4];
                    f32x4 cur = *(f32x4*)p;
                    cur += o[mt][dt];
                    *(f32x4*)p = cur;
                }
        }
        __syncthreads();
    }
    // Final: combine the two buffers, normalize, store bf16 (512 threads)
    {
        const int row = t >> 4;             // 0..31
        const int d0  = (t & 15) << 2;      // 4 bf16 per thread
        float l = 0.f;
        #pragma unroll
        for (int wi = 0; wi < 8; ++wi) l += lbuf[wi * 32 + row];
        const float inv = 1.0f / l;
        const int c = row * 66 + d0;
        const float v0 = (Ob[0][c + 0] + Ob[1][c + 0]) * inv;
        const float v1 = (Ob[0][c + 1] + Ob[1][c + 1]) * inv;
        const float v2 = (Ob[0][c + 2] + Ob[1][c + 2]) * inv;
        const float v3 = (Ob[0][c + 3] + Ob[1][c + 3]) * inv;
        uint2 rv = { pk2(v0, v1), pk2(v2, v3) };
        short* op = Ogb + ((size_t)(b * NQ + qt * 32 + row)) * 512 + h * 64 + d0;
        *(uint2*)op = rv;
    }
}

// ---------------------------------------------------------------------------
extern "C" void kernel_launch(void* const* d_in, const int* in_sizes, int n_in,
                              void* d_out, int out_size, void* d_ws, size_t ws_size,
                              hipStream_t stream) {
    (void)in_sizes; (void)n_in; (void)out_size; (void)ws_size;

    const float* x   = (const float*)d_in[0];   // [4, 512, 512]
    const float* ctx = (const float*)d_in[1];   // [4, 8192, 256]
    const float* Wq  = (const float*)d_in[2];   // [512, 512]
    const float* Wkv = (const float*)d_in[3];   // [256, 1024]
    const float* Wo  = (const float*)d_in[4];   // [512, 512]
    const float* bo  = (const float*)d_in[5];   // [512]
    float* out = (float*)d_out;                 // [4, 512, 512]

    float* ws    = (float*)d_ws;
    float* q     = ws;                                       // 4 MB fp32
    short* attnb = (short*)(q + (size_t)2048 * 512);         // 2 MB bf16
    short* Kf    = attnb + (size_t)2048 * 512;               // 33.5 MB bf16 (fragment order)
    short* Vf    = Kf + (size_t)NB * NH * NM * DH;           // 33.5 MB bf16 (fragment order)
    short* Wqf   = Vf + (size_t)NB * NH * NM * DH;           // 512 KB
    short* Wof   = Wqf + (size_t)512 * 512;                  // 512 KB
    short* Wkvf  = Wof + (size_t)512 * 512;                  // 512 KB

    // weights -> bf16 fragment order
    prep_weights<<<dim3(384), dim3(256), 0, stream>>>(Wq, Wo, Wkv, Wqf, Wof, Wkvf);

    // q = x@Wq (256 blocks x 2 units) + kv = ctx@Wkv (2048 blocks), 512 thr
    gemm_kvq<<<dim3(2304), dim3(512), 0, stream>>>(x, Wqf, q, ctx, Wkvf, Kf, Vf);

    // flash attention: 32 bh x 16 q-tiles = 512 blocks x 512 threads
    attn_mfma<<<dim3(512), dim3(512), 0, stream>>>(q, Kf, Vf, attnb);

    // out = attnb @ Wo + bo (512 blocks, coalesced LDS-staged bf16-A path)
    gemm_projo<<<dim3(512), dim3(256), 0, stream>>>(attnb, Wof, out, bo);
}